// Round 1
// baseline (211.342 us; speedup 1.0000x reference)
//
#include <hip/hip_runtime.h>
#include <math.h>

#define C 10
#define BLOCK 256
#define NBLOCKS 1024
#define WROWS 128                    // rows per wave-tile
#define WELEMS (WROWS * C)           // 1280 floats = 5 KB per buffer
#define NSTATS (3 * C)               // 30 series

typedef float f4 __attribute__((ext_vector_type(4)));

#define NTL4(p) __builtin_nontemporal_load(p)

// ---------------- row accumulate (softmax sufficient statistics) ----------------

__device__ __forceinline__ void accum_row(const float* __restrict__ row,
                                          float* __restrict__ s1,
                                          float* __restrict__ s2,
                                          float* __restrict__ sl) {
  float v[C];
#pragma unroll
  for (int c = 0; c < C; c++) v[c] = row[c];
  float mx = v[0];
#pragma unroll
  for (int c = 1; c < C; c++) mx = fmaxf(mx, v[c]);
  float e[C], se = 0.f;
#pragma unroll
  for (int c = 0; c < C; c++) { v[c] -= mx; e[c] = __expf(v[c]); se += e[c]; }
  float inv = 1.0f / se;
  float lse = __logf(se);
#pragma unroll
  for (int c = 0; c < C; c++) {
    float p = e[c] * inv;
    s1[c] += p;
    s2[c] = fmaf(p, p, s2[c]);
    sl[c] += v[c] - lse;             // log p = (x - mx) - lse
  }
}

// ---------------- fp64 digamma/trigamma via shift-8 + asymptotic ----------------

__device__ __forceinline__ void digtri8(double x, double& dg, double& tg) {
  double i0 = 1.0 / x,         i1 = 1.0 / (x + 1.0);
  double i2 = 1.0 / (x + 2.0), i3 = 1.0 / (x + 3.0);
  double i4 = 1.0 / (x + 4.0), i5 = 1.0 / (x + 5.0);
  double i6 = 1.0 / (x + 6.0), i7 = 1.0 / (x + 7.0);
  double rd = (i0 + i1) + (i2 + i3) + ((i4 + i5) + (i6 + i7));
  double rt = (i0 * i0 + i1 * i1) + (i2 * i2 + i3 * i3) +
              ((i4 * i4 + i5 * i5) + (i6 * i6 + i7 * i7));
  double y = x + 8.0;
  double yi = 1.0 / y, f = yi * yi;
  dg = log(y) - 0.5 * yi
     - f * (1.0 / 12 - f * (1.0 / 120 - f * (1.0 / 252 - f * (1.0 / 240 - f * (1.0 / 132)))))
     - rd;
  tg = rt + yi + 0.5 * f
     + f * yi * (1.0 / 6 - f * (1.0 / 30 - f * (1.0 / 42 - f * (1.0 / 30))));
}

__device__ __forceinline__ double wsum16(double v) {
#pragma unroll
  for (int off = 1; off < 16; off <<= 1) v += __shfl_xor(v, off);
  return v;
}

// ---------------- Fused kernel: stats + last-block reduce/Newton ----------------
// Stats phase: each wave owns a private 2x5KB LDS double-buffer, grid-strides over
// 128-row wave-tiles, ZERO barriers in the hot loop (wave-private buffers).
// Finish phase: threadfence + device-scope atomic counter; the LAST block to
// finish reduces the 30 x nblocks partials and runs the fp64 Newton solve.

__global__ __launch_bounds__(BLOCK) void dir_fused_kernel(
    const float* __restrict__ x, float* __restrict__ out,
    float* __restrict__ partials, unsigned int* __restrict__ ctr,
    int nrows, int nblocks, double nd) {
  __shared__ float buf[4][2][WELEMS];        // 4 waves x 2 phases x 5 KB = 40 KB
  __shared__ float red[4][NSTATS];
  __shared__ double totd[32];
  __shared__ int lastFlag;

  const int tid = threadIdx.x;
  const int lane = tid & 63;
  const int wave = tid >> 6;

  const int gwave = blockIdx.x * 4 + wave;   // global wave id
  const int wstride = nblocks * 4;
  const int ntiles = nrows / WROWS;
  const int tailStart = ntiles * WROWS;

  float s1[C], s2[C], sl[C];
#pragma unroll
  for (int c = 0; c < C; c++) { s1[c] = 0.f; s2[c] = 0.f; sl[c] = 0.f; }

  int g = gwave;
  f4 a0 = 0, a1 = 0, a2 = 0, a3 = 0, a4 = 0;
  if (g < ntiles) {                          // prologue prefetch (coalesced 1 KB/step)
    const f4* __restrict__ p = (const f4*)(x + (size_t)g * WELEMS) + lane;
    a0 = NTL4(p); a1 = NTL4(p + 64); a2 = NTL4(p + 128);
    a3 = NTL4(p + 192); a4 = NTL4(p + 256);
  }
  int phase = 0;
  while (g < ntiles) {
    f4* dst = (f4*)buf[wave][phase] + lane;  // wave-private: no barrier needed
    dst[0] = a0; dst[64] = a1; dst[128] = a2; dst[192] = a3; dst[256] = a4;

    const int gn = g + wstride;              // issue next tile's loads NOW
    if (gn < ntiles) {
      const f4* __restrict__ p = (const f4*)(x + (size_t)gn * WELEMS) + lane;
      a0 = NTL4(p); a1 = NTL4(p + 64); a2 = NTL4(p + 128);
      a3 = NTL4(p + 192); a4 = NTL4(p + 256);
    }

    // same-wave ds ordering + compiler lgkm waits make this safe barrier-free
    accum_row(buf[wave][phase] + (size_t)lane * C, s1, s2, sl);
    accum_row(buf[wave][phase] + (size_t)(64 + lane) * C, s1, s2, sl);

    g = gn; phase ^= 1;
  }

  if (gwave == wstride - 1) {                // tail rows (none when nrows%128==0)
    for (int rr = tailStart + lane; rr < nrows; rr += 64) {
      float v[C];
      const float* r = x + (size_t)rr * C;
#pragma unroll
      for (int c = 0; c < C; c++) v[c] = r[c];
      float mx = v[0];
#pragma unroll
      for (int c = 1; c < C; c++) mx = fmaxf(mx, v[c]);
      float e[C], se = 0.f;
#pragma unroll
      for (int c = 0; c < C; c++) { v[c] -= mx; e[c] = __expf(v[c]); se += e[c]; }
      float inv = 1.0f / se, lse = __logf(se);
#pragma unroll
      for (int c = 0; c < C; c++) {
        float p = e[c] * inv;
        s1[c] += p; s2[c] = fmaf(p, p, s2[c]); sl[c] += v[c] - lse;
      }
    }
  }

  // block reduction: wave shuffle, then cross-wave via LDS (single barrier, post-loop)
#pragma unroll
  for (int c = 0; c < C; c++) {
    float v1 = s1[c], v2 = s2[c], v3 = sl[c];
#pragma unroll
    for (int off = 32; off >= 1; off >>= 1) {
      v1 += __shfl_down(v1, off);
      v2 += __shfl_down(v2, off);
      v3 += __shfl_down(v3, off);
    }
    if (lane == 0) {
      red[wave][c] = v1;
      red[wave][C + c] = v2;
      red[wave][2 * C + c] = v3;
    }
  }
  __syncthreads();
  if (tid < NSTATS) {
    float tot = red[0][tid] + red[1][tid] + red[2][tid] + red[3][tid];
    partials[(size_t)tid * nblocks + blockIdx.x] = tot;   // SoA over blocks
  }

  // ---- last-block-finishes pattern (CUDA threadFenceReduction idiom) ----
  __threadfence();                           // release partials to device scope
  __syncthreads();                           // order all writes before tid0's atomic
  if (tid == 0)
    lastFlag = (atomicAdd(ctr, 1u) == (unsigned)(nblocks - 1));
  __syncthreads();
  if (!lastFlag) return;
  __threadfence();                           // acquire all blocks' partials

  // ---- final reduce: 256 threads over 30 x nblocks partials (L2-resident) ----
  {
    const int j = tid >> 3;                  // series 0..31 (30 active)
    const int k = tid & 7;
    double s = 0.0;
    if (j < NSTATS) {
      const float* __restrict__ base = partials + (size_t)j * nblocks;
#pragma unroll 8
      for (int b = k; b < nblocks; b += 8) s += (double)base[b];
    }
    // 8-lane tree (groups of 8 contiguous lanes, same wave)
    s += __shfl_down(s, 4);
    s += __shfl_down(s, 2);
    s += __shfl_down(s, 1);
    if (j < NSTATS && k == 0) totd[j] = s;
  }
  __syncthreads();

  // ---- fp64 Newton with rank-1 Hessian inverse, 16 lanes ----
  if (tid < 16) {
    const int c = tid;
    const bool act = (c < C);
    const double n = nd;
    double m1 = 0.0, m2 = 0.0, lpa = 0.0;
    if (act) {
      m1 = totd[c] / n;
      m2 = totd[C + c] / n;
      lpa = totd[2 * C + c] / n;
    }
    double ratio = act ? (m1 - m2) / (m2 - m1 * m1) : 0.0;
    double rmean = wsum16(ratio) / (double)C;
    double a = act ? m1 * rmean : 0.0;

    double diff = 1e30;
    for (int k = 0; k < 100 && diff >= 1e-3; k++) {
      double S = wsum16(a);             // lanes 10..15 hold 0
      double dgl, tgl;                  // lanes 0..9: digtri(a); lane 10+: digtri(S)
      digtri8(act ? a : S, dgl, tgl);
      double dgS = __shfl(dgl, 10);
      double tgS = __shfl(tgl, 10);
      double g = act ? (dgS - dgl + lpa) * n : 0.0;
      double qinv = act ? (-1.0) / (n * tgl) : 0.0;
      double z = n * tgS;
      double num = wsum16(g * qinv);
      double den = 1.0 / z + wsum16(qinv);
      double b = num / den;
      double anew = act ? a - (g - b) * qinv : 0.0;
      diff = wsum16(fabs(anew - a));
      a = anew;
    }
    if (act) out[c] = (float)a;
  }
}

// ---------------- launch ----------------

extern "C" void kernel_launch(void* const* d_in, const int* in_sizes, int n_in,
                              void* d_out, int out_size, void* d_ws, size_t ws_size,
                              hipStream_t stream) {
  const float* x = (const float*)d_in[0];
  const int total = in_sizes[0];
  const int nrows = total / C;

  // workspace layout: [0..63] counter (aligned pad), then 30 x grid partials
  int grid = NBLOCKS;
  size_t need = 64 + (size_t)NSTATS * grid * sizeof(float);
  if (need > ws_size) {
    grid = (int)((ws_size - 64) / (NSTATS * sizeof(float)));
    if (grid < 1) grid = 1;
  }

  unsigned int* ctr = (unsigned int*)d_ws;
  float* partials = (float*)((char*)d_ws + 64);

  hipMemsetAsync(d_ws, 0, sizeof(unsigned int), stream);   // graph-capturable node
  dir_fused_kernel<<<grid, BLOCK, 0, stream>>>(x, (float*)d_out, partials, ctr,
                                               nrows, grid, (double)nrows);
}

// Round 2
// 130.794 us; speedup vs baseline: 1.6158x; 1.6158x over previous
//
#include <hip/hip_runtime.h>
#include <math.h>

#define C 10
#define BLOCK 256
#define NBLOCKS 1024
#define WROWS 128                    // rows per wave-tile
#define WELEMS (WROWS * C)           // 1280 floats = 5 KB per buffer
#define NSTATS (3 * C)               // 30 series

typedef float f4 __attribute__((ext_vector_type(4)));

// ---------------- row accumulate (softmax sufficient statistics) ----------------

__device__ __forceinline__ void accum_row(const float* __restrict__ row,
                                          float* __restrict__ s1,
                                          float* __restrict__ s2,
                                          float* __restrict__ sl) {
  float v[C];
#pragma unroll
  for (int c = 0; c < C; c++) v[c] = row[c];
  float mx = v[0];
#pragma unroll
  for (int c = 1; c < C; c++) mx = fmaxf(mx, v[c]);
  float e[C], se = 0.f;
#pragma unroll
  for (int c = 0; c < C; c++) { v[c] -= mx; e[c] = __expf(v[c]); se += e[c]; }
  float inv = 1.0f / se;
  float lse = __logf(se);
#pragma unroll
  for (int c = 0; c < C; c++) {
    float p = e[c] * inv;
    s1[c] += p;
    s2[c] = fmaf(p, p, s2[c]);
    sl[c] += v[c] - lse;             // log p = (x - mx) - lse
  }
}

// ---------------- fp64 digamma/trigamma via shift-8 + asymptotic ----------------

__device__ __forceinline__ void digtri8(double x, double& dg, double& tg) {
  double i0 = 1.0 / x,         i1 = 1.0 / (x + 1.0);
  double i2 = 1.0 / (x + 2.0), i3 = 1.0 / (x + 3.0);
  double i4 = 1.0 / (x + 4.0), i5 = 1.0 / (x + 5.0);
  double i6 = 1.0 / (x + 6.0), i7 = 1.0 / (x + 7.0);
  double rd = (i0 + i1) + (i2 + i3) + ((i4 + i5) + (i6 + i7));
  double rt = (i0 * i0 + i1 * i1) + (i2 * i2 + i3 * i3) +
              ((i4 * i4 + i5 * i5) + (i6 * i6 + i7 * i7));
  double y = x + 8.0;
  double yi = 1.0 / y, f = yi * yi;
  dg = log(y) - 0.5 * yi
     - f * (1.0 / 12 - f * (1.0 / 120 - f * (1.0 / 252 - f * (1.0 / 240 - f * (1.0 / 132)))))
     - rd;
  tg = rt + yi + 0.5 * f
     + f * yi * (1.0 / 6 - f * (1.0 / 30 - f * (1.0 / 42 - f * (1.0 / 30))));
}

__device__ __forceinline__ double wsum16(double v) {
#pragma unroll
  for (int off = 1; off < 16; off <<= 1) v += __shfl_xor(v, off);
  return v;
}

// ---------------- Fused kernel: stats + last-block reduce/Newton ----------------
// Stats phase: wave-private 2x5KB LDS double-buffer, zero barriers in the hot loop.
// Finish phase: FENCE-FREE last-block pattern. NO __threadfence() — on gfx950 an
// agent-scope fence lowers to a whole-L2 writeback (buffer_wbl2) per block, which
// serialized the tail in the previous version (WRITE_SIZE showed 8x amplification).
// Instead: partials are written with agent-scope relaxed stores (sc1 -> bypass the
// non-coherent per-XCD L2, complete at the coherence point), ordered before the
// ticket atomic by a single s_waitcnt vmcnt(0) in the storing wave. The last block
// reads them back with agent-scope relaxed loads (sc1 -> not stale-L2-served).

__global__ __launch_bounds__(BLOCK) void dir_fused_kernel(
    const float* __restrict__ x, float* __restrict__ out,
    float* __restrict__ partials, unsigned int* __restrict__ ctr,
    int nrows, int nblocks, double nd) {
  __shared__ float buf[4][2][WELEMS];        // 4 waves x 2 phases x 5 KB = 40 KB
  __shared__ float red[4][NSTATS];
  __shared__ double totd[32];
  __shared__ int lastFlag;

  const int tid = threadIdx.x;
  const int lane = tid & 63;
  const int wave = tid >> 6;

  const int gwave = blockIdx.x * 4 + wave;   // global wave id
  const int wstride = nblocks * 4;
  const int ntiles = nrows / WROWS;
  const int tailStart = ntiles * WROWS;

  float s1[C], s2[C], sl[C];
#pragma unroll
  for (int c = 0; c < C; c++) { s1[c] = 0.f; s2[c] = 0.f; sl[c] = 0.f; }

  int g = gwave;
  f4 a0 = 0, a1 = 0, a2 = 0, a3 = 0, a4 = 0;
  if (g < ntiles) {                          // prologue prefetch (coalesced 1 KB/step)
    const f4* __restrict__ p = (const f4*)(x + (size_t)g * WELEMS) + lane;
    a0 = p[0]; a1 = p[64]; a2 = p[128]; a3 = p[192]; a4 = p[256];
  }
  int phase = 0;
  while (g < ntiles) {
    f4* dst = (f4*)buf[wave][phase] + lane;  // wave-private: no barrier needed
    dst[0] = a0; dst[64] = a1; dst[128] = a2; dst[192] = a3; dst[256] = a4;

    const int gn = g + wstride;              // issue next tile's loads NOW
    if (gn < ntiles) {
      const f4* __restrict__ p = (const f4*)(x + (size_t)gn * WELEMS) + lane;
      a0 = p[0]; a1 = p[64]; a2 = p[128]; a3 = p[192]; a4 = p[256];
    }

    // same-wave ds ordering + compiler lgkm waits make this safe barrier-free
    accum_row(buf[wave][phase] + (size_t)lane * C, s1, s2, sl);
    accum_row(buf[wave][phase] + (size_t)(64 + lane) * C, s1, s2, sl);

    g = gn; phase ^= 1;
  }

  if (gwave == wstride - 1) {                // tail rows (none when nrows%128==0)
    for (int rr = tailStart + lane; rr < nrows; rr += 64) {
      float v[C];
      const float* r = x + (size_t)rr * C;
#pragma unroll
      for (int c = 0; c < C; c++) v[c] = r[c];
      float mx = v[0];
#pragma unroll
      for (int c = 1; c < C; c++) mx = fmaxf(mx, v[c]);
      float e[C], se = 0.f;
#pragma unroll
      for (int c = 0; c < C; c++) { v[c] -= mx; e[c] = __expf(v[c]); se += e[c]; }
      float inv = 1.0f / se, lse = __logf(se);
#pragma unroll
      for (int c = 0; c < C; c++) {
        float p = e[c] * inv;
        s1[c] += p; s2[c] = fmaf(p, p, s2[c]); sl[c] += v[c] - lse;
      }
    }
  }

  // block reduction: wave shuffle, then cross-wave via LDS (single barrier, post-loop)
#pragma unroll
  for (int c = 0; c < C; c++) {
    float v1 = s1[c], v2 = s2[c], v3 = sl[c];
#pragma unroll
    for (int off = 32; off >= 1; off >>= 1) {
      v1 += __shfl_down(v1, off);
      v2 += __shfl_down(v2, off);
      v3 += __shfl_down(v3, off);
    }
    if (lane == 0) {
      red[wave][c] = v1;
      red[wave][C + c] = v2;
      red[wave][2 * C + c] = v3;
    }
  }
  __syncthreads();

  // ---- publish partials: agent-scope relaxed stores (sc1), no L2 flush ----
  if (tid < NSTATS) {
    float tot = red[0][tid] + red[1][tid] + red[2][tid] + red[3][tid];
    __hip_atomic_store(partials + (size_t)tid * nblocks + blockIdx.x, tot,
                       __ATOMIC_RELAXED, __HIP_MEMORY_SCOPE_AGENT);
  }
  // tid 0..29 are all in wave 0; tid0's scalar waitcnt covers the 30 stores
  if (tid == 0) {
    asm volatile("s_waitcnt vmcnt(0)" ::: "memory");  // stores ack'd at coherence pt
    unsigned prev = atomicAdd(ctr, 1u);               // relaxed device-scope ticket
    lastFlag = (prev == (unsigned)(nblocks - 1));
  }
  __syncthreads();
  if (!lastFlag) return;

  // ---- final reduce: 256 threads over 30 x nblocks partials (sc1 loads) ----
  {
    const int j = tid >> 3;                  // series 0..31 (30 active)
    const int k = tid & 7;
    double s = 0.0;
    if (j < NSTATS) {
      const float* __restrict__ base = partials + (size_t)j * nblocks;
#pragma unroll 8
      for (int b = k; b < nblocks; b += 8)
        s += (double)__hip_atomic_load(base + b, __ATOMIC_RELAXED,
                                       __HIP_MEMORY_SCOPE_AGENT);
    }
    // 8-lane tree (groups of 8 contiguous lanes, same wave)
    s += __shfl_down(s, 4);
    s += __shfl_down(s, 2);
    s += __shfl_down(s, 1);
    if (j < NSTATS && k == 0) totd[j] = s;
  }
  __syncthreads();

  // ---- fp64 Newton with rank-1 Hessian inverse, 16 lanes ----
  if (tid < 16) {
    const int c = tid;
    const bool act = (c < C);
    const double n = nd;
    double m1 = 0.0, m2 = 0.0, lpa = 0.0;
    if (act) {
      m1 = totd[c] / n;
      m2 = totd[C + c] / n;
      lpa = totd[2 * C + c] / n;
    }
    double ratio = act ? (m1 - m2) / (m2 - m1 * m1) : 0.0;
    double rmean = wsum16(ratio) / (double)C;
    double a = act ? m1 * rmean : 0.0;

    double diff = 1e30;
    for (int k = 0; k < 100 && diff >= 1e-3; k++) {
      double S = wsum16(a);             // lanes 10..15 hold 0
      double dgl, tgl;                  // lanes 0..9: digtri(a); lane 10+: digtri(S)
      digtri8(act ? a : S, dgl, tgl);
      double dgS = __shfl(dgl, 10);
      double tgS = __shfl(tgl, 10);
      double g = act ? (dgS - dgl + lpa) * n : 0.0;
      double qinv = act ? (-1.0) / (n * tgl) : 0.0;
      double z = n * tgS;
      double num = wsum16(g * qinv);
      double den = 1.0 / z + wsum16(qinv);
      double b = num / den;
      double anew = act ? a - (g - b) * qinv : 0.0;
      diff = wsum16(fabs(anew - a));
      a = anew;
    }
    if (act) out[c] = (float)a;
  }
}

// ---------------- launch ----------------

extern "C" void kernel_launch(void* const* d_in, const int* in_sizes, int n_in,
                              void* d_out, int out_size, void* d_ws, size_t ws_size,
                              hipStream_t stream) {
  const float* x = (const float*)d_in[0];
  const int total = in_sizes[0];
  const int nrows = total / C;

  // workspace layout: [0..63] counter (aligned pad), then 30 x grid partials
  int grid = NBLOCKS;
  size_t need = 64 + (size_t)NSTATS * grid * sizeof(float);
  if (need > ws_size) {
    grid = (int)((ws_size - 64) / (NSTATS * sizeof(float)));
    if (grid < 1) grid = 1;
  }

  unsigned int* ctr = (unsigned int*)d_ws;
  float* partials = (float*)((char*)d_ws + 64);

  hipMemsetAsync(d_ws, 0, sizeof(unsigned int), stream);   // graph-capturable node
  dir_fused_kernel<<<grid, BLOCK, 0, stream>>>(x, (float*)d_out, partials, ctr,
                                               nrows, grid, (double)nrows);
}

// Round 3
// 120.729 us; speedup vs baseline: 1.7505x; 1.0834x over previous
//
#include <hip/hip_runtime.h>
#include <math.h>

#define C 10
#define BLOCK 256
#define NBLOCKS 1024
#define WROWS 128                    // rows per wave-tile (2 rows per lane)
#define NSTATS (3 * C)               // 30 series

// 4B-aligned vector types: row base addresses are 40B multiples, so only
// dword alignment is guaranteed. gfx9+ global_load_dwordx4 needs only 4B.
typedef float f4 __attribute__((ext_vector_type(4), aligned(4)));
typedef float f2 __attribute__((ext_vector_type(2), aligned(4)));

// ---------------- row accumulate (softmax sufficient statistics) ----------------

__device__ __forceinline__ void accum10(f4 r0, f4 r1, f2 r2,
                                        float* __restrict__ s1,
                                        float* __restrict__ s2,
                                        float* __restrict__ sl) {
  float v[C];
  v[0] = r0.x; v[1] = r0.y; v[2] = r0.z; v[3] = r0.w;
  v[4] = r1.x; v[5] = r1.y; v[6] = r1.z; v[7] = r1.w;
  v[8] = r2.x; v[9] = r2.y;
  float mx = v[0];
#pragma unroll
  for (int c = 1; c < C; c++) mx = fmaxf(mx, v[c]);
  float e[C], se = 0.f;
#pragma unroll
  for (int c = 0; c < C; c++) { v[c] -= mx; e[c] = __expf(v[c]); se += e[c]; }
  float inv = 1.0f / se;
  float lse = __logf(se);
#pragma unroll
  for (int c = 0; c < C; c++) {
    float p = e[c] * inv;
    s1[c] += p;
    s2[c] = fmaf(p, p, s2[c]);
    sl[c] += v[c] - lse;             // log p = (x - mx) - lse
  }
}

// ---------------- Kernel 1: LDS-free stats, register double-buffer ----------------
// Each lane loads its own 40B row directly (f4+f4+f2, all dword-aligned); a wave's
// 64 rows span one contiguous 2.5KB block -> DRAM-efficient, L1 absorbs the line
// overlap between the three loads. Next tile's 2 rows are prefetched into registers
// while the current tile computes: no LDS ping-pong, no vmcnt(0)/lgkm drains, and
// LDS drops 40KB -> 480B so all 1024 blocks are resident in ONE scheduling round.

__global__ __launch_bounds__(BLOCK) void dir_stats_kernel(
    const float* __restrict__ x, float* __restrict__ partials,
    int nrows, int nblocks) {
  __shared__ float red[4][NSTATS];
  const int tid = threadIdx.x;
  const int lane = tid & 63;
  const int wave = tid >> 6;

  const int gwave = blockIdx.x * 4 + wave;   // global wave id
  const int wstride = nblocks * 4;
  const int ntiles = nrows / WROWS;
  const int tailStart = ntiles * WROWS;

  float s1[C], s2[C], sl[C];
#pragma unroll
  for (int c = 0; c < C; c++) { s1[c] = 0.f; s2[c] = 0.f; sl[c] = 0.f; }

  int g = gwave;
  f4 a0 = 0, a1 = 0, b0 = 0, b1 = 0, n0 = 0, n1 = 0, m0 = 0, m1 = 0;
  f2 a2 = 0, b2 = 0, n2 = 0, m2 = 0;
  if (g < ntiles) {                          // prologue: rows (g*128+lane), (+64)
    const float* p = x + ((size_t)g * WROWS + lane) * C;
    a0 = *(const f4*)(p);       a1 = *(const f4*)(p + 4);   a2 = *(const f2*)(p + 8);
    b0 = *(const f4*)(p + 640); b1 = *(const f4*)(p + 644); b2 = *(const f2*)(p + 648);
  }
  while (g < ntiles) {
    const int gn = g + wstride;              // issue next tile's loads NOW
    if (gn < ntiles) {
      const float* p = x + ((size_t)gn * WROWS + lane) * C;
      n0 = *(const f4*)(p);       n1 = *(const f4*)(p + 4);   n2 = *(const f2*)(p + 8);
      m0 = *(const f4*)(p + 640); m1 = *(const f4*)(p + 644); m2 = *(const f2*)(p + 648);
    }
    accum10(a0, a1, a2, s1, s2, sl);         // compute on current regs (no dep on loads)
    accum10(b0, b1, b2, s1, s2, sl);
    a0 = n0; a1 = n1; a2 = n2;               // vmcnt wait lands here, after compute
    b0 = m0; b1 = m1; b2 = m2;
    g = gn;
  }

  if (gwave == wstride - 1) {                // tail rows (none when nrows%128==0)
    for (int rr = tailStart + lane; rr < nrows; rr += 64) {
      const float* r = x + (size_t)rr * C;
      f4 t0 = *(const f4*)(r);
      f4 t1 = *(const f4*)(r + 4);
      f2 t2 = *(const f2*)(r + 8);
      accum10(t0, t1, t2, s1, s2, sl);
    }
  }

  // block reduction: wave shuffle, then cross-wave via LDS (single barrier)
#pragma unroll
  for (int c = 0; c < C; c++) {
    float v1 = s1[c], v2 = s2[c], v3 = sl[c];
#pragma unroll
    for (int off = 32; off >= 1; off >>= 1) {
      v1 += __shfl_down(v1, off);
      v2 += __shfl_down(v2, off);
      v3 += __shfl_down(v3, off);
    }
    if (lane == 0) {
      red[wave][c] = v1;
      red[wave][C + c] = v2;
      red[wave][2 * C + c] = v3;
    }
  }
  __syncthreads();
  if (tid < NSTATS) {
    float tot = red[0][tid] + red[1][tid] + red[2][tid] + red[3][tid];
    partials[(size_t)tid * nblocks + blockIdx.x] = tot;   // SoA over blocks
  }
}

// ---------------- fp64 digamma/trigamma via shift-8 + asymptotic ----------------

__device__ __forceinline__ void digtri8(double x, double& dg, double& tg) {
  double i0 = 1.0 / x,         i1 = 1.0 / (x + 1.0);
  double i2 = 1.0 / (x + 2.0), i3 = 1.0 / (x + 3.0);
  double i4 = 1.0 / (x + 4.0), i5 = 1.0 / (x + 5.0);
  double i6 = 1.0 / (x + 6.0), i7 = 1.0 / (x + 7.0);
  double rd = (i0 + i1) + (i2 + i3) + ((i4 + i5) + (i6 + i7));
  double rt = (i0 * i0 + i1 * i1) + (i2 * i2 + i3 * i3) +
              ((i4 * i4 + i5 * i5) + (i6 * i6 + i7 * i7));
  double y = x + 8.0;
  double yi = 1.0 / y, f = yi * yi;
  dg = log(y) - 0.5 * yi
     - f * (1.0 / 12 - f * (1.0 / 120 - f * (1.0 / 252 - f * (1.0 / 240 - f * (1.0 / 132)))))
     - rd;
  tg = rt + yi + 0.5 * f
     + f * yi * (1.0 / 6 - f * (1.0 / 30 - f * (1.0 / 42 - f * (1.0 / 30))));
}

__device__ __forceinline__ double wsum16(double v) {
#pragma unroll
  for (int off = 1; off < 16; off <<= 1) v += __shfl_xor(v, off);
  return v;
}

// ---------------- Kernel 2: MLP-parallel reduce + Newton (fp64) ----------------

__global__ __launch_bounds__(1024) void dir_newton_kernel(
    const float* __restrict__ partials, float* __restrict__ out,
    int nparts, double nrows) {
  __shared__ double tot[NSTATS];
  const int tid = threadIdx.x;

  {
    const int j = tid >> 5;        // series (30 active of 32)
    const int k = tid & 31;
    double s = 0.0;
    if (j < NSTATS) {
      const float* __restrict__ base = partials + (size_t)j * nparts;
#pragma unroll 8
      for (int b = k; b < nparts; b += 32)
        s += (double)base[b];
    }
#pragma unroll
    for (int off = 16; off >= 1; off >>= 1) s += __shfl_xor(s, off);
    if (j < NSTATS && k == 0) tot[j] = s;
  }
  __syncthreads();

  if (tid < 16) {
    const int c = tid;
    const bool act = (c < C);
    const double n = nrows;
    double m1 = 0.0, m2 = 0.0, lpa = 0.0;
    if (act) {
      m1 = tot[c] / n;
      m2 = tot[C + c] / n;
      lpa = tot[2 * C + c] / n;
    }
    double ratio = act ? (m1 - m2) / (m2 - m1 * m1) : 0.0;
    double rmean = wsum16(ratio) / (double)C;
    double a = act ? m1 * rmean : 0.0;

    double diff = 1e30;
    for (int k = 0; k < 100 && diff >= 1e-3; k++) {
      double S = wsum16(a);             // lanes 10..15 hold 0
      double dgl, tgl;                  // lanes 0..9: digtri(a); lane 10+: digtri(S)
      digtri8(act ? a : S, dgl, tgl);
      double dgS = __shfl(dgl, 10);
      double tgS = __shfl(tgl, 10);
      double g = act ? (dgS - dgl + lpa) * n : 0.0;
      double qinv = act ? (-1.0) / (n * tgl) : 0.0;
      double z = n * tgS;
      double num = wsum16(g * qinv);
      double den = 1.0 / z + wsum16(qinv);
      double b = num / den;
      double anew = act ? a - (g - b) * qinv : 0.0;
      diff = wsum16(fabs(anew - a));
      a = anew;
    }
    if (act) out[c] = (float)a;
  }
}

// ---------------- launch ----------------

extern "C" void kernel_launch(void* const* d_in, const int* in_sizes, int n_in,
                              void* d_out, int out_size, void* d_ws, size_t ws_size,
                              hipStream_t stream) {
  const float* x = (const float*)d_in[0];
  const int total = in_sizes[0];
  const int nrows = total / C;

  int grid = NBLOCKS;
  size_t need = (size_t)NSTATS * grid * sizeof(float);
  if (need > ws_size) {
    grid = (int)(ws_size / (NSTATS * sizeof(float)));
    if (grid < 1) grid = 1;
  }

  float* partials = (float*)d_ws;
  dir_stats_kernel<<<grid, BLOCK, 0, stream>>>(x, partials, nrows, grid);
  dir_newton_kernel<<<1, 1024, 0, stream>>>(partials, (float*)d_out, grid, (double)nrows);
}

// Round 4
// 119.393 us; speedup vs baseline: 1.7701x; 1.0112x over previous
//
#include <hip/hip_runtime.h>
#include <math.h>

#define C 10
#define BLOCK 256
#define NBLOCKS 1024
#define WROWS 128                    // rows per wave-tile (2 rows per lane)
#define NSTATS (3 * C)               // 30 series

// 4B-aligned vector types: row base addresses are 40B multiples, so only
// dword alignment is guaranteed. gfx9+ global_load_dwordx4 needs only 4B.
typedef float f4 __attribute__((ext_vector_type(4), aligned(4)));
typedef float f2 __attribute__((ext_vector_type(2), aligned(4)));

// ---------------- row accumulate (softmax sufficient statistics) ----------------

__device__ __forceinline__ void accum10(f4 r0, f4 r1, f2 r2,
                                        float* __restrict__ s1,
                                        float* __restrict__ s2,
                                        float* __restrict__ sl) {
  float v[C];
  v[0] = r0.x; v[1] = r0.y; v[2] = r0.z; v[3] = r0.w;
  v[4] = r1.x; v[5] = r1.y; v[6] = r1.z; v[7] = r1.w;
  v[8] = r2.x; v[9] = r2.y;
  float mx = v[0];
#pragma unroll
  for (int c = 1; c < C; c++) mx = fmaxf(mx, v[c]);
  float e[C], se = 0.f;
#pragma unroll
  for (int c = 0; c < C; c++) { v[c] -= mx; e[c] = __expf(v[c]); se += e[c]; }
  float inv = 1.0f / se;
  float lse = __logf(se);
#pragma unroll
  for (int c = 0; c < C; c++) {
    float p = e[c] * inv;
    s1[c] += p;
    s2[c] = fmaf(p, p, s2[c]);
    sl[c] += v[c] - lse;             // log p = (x - mx) - lse
  }
}

// ---------------- Kernel 1: LDS-free stats, register double-buffer ----------------
// (unchanged from previous round — control variable for this round's attribution)

__global__ __launch_bounds__(BLOCK) void dir_stats_kernel(
    const float* __restrict__ x, float* __restrict__ partials,
    int nrows, int nblocks) {
  __shared__ float red[4][NSTATS];
  const int tid = threadIdx.x;
  const int lane = tid & 63;
  const int wave = tid >> 6;

  const int gwave = blockIdx.x * 4 + wave;   // global wave id
  const int wstride = nblocks * 4;
  const int ntiles = nrows / WROWS;
  const int tailStart = ntiles * WROWS;

  float s1[C], s2[C], sl[C];
#pragma unroll
  for (int c = 0; c < C; c++) { s1[c] = 0.f; s2[c] = 0.f; sl[c] = 0.f; }

  int g = gwave;
  f4 a0 = 0, a1 = 0, b0 = 0, b1 = 0, n0 = 0, n1 = 0, m0 = 0, m1 = 0;
  f2 a2 = 0, b2 = 0, n2 = 0, m2 = 0;
  if (g < ntiles) {                          // prologue: rows (g*128+lane), (+64)
    const float* p = x + ((size_t)g * WROWS + lane) * C;
    a0 = *(const f4*)(p);       a1 = *(const f4*)(p + 4);   a2 = *(const f2*)(p + 8);
    b0 = *(const f4*)(p + 640); b1 = *(const f4*)(p + 644); b2 = *(const f2*)(p + 648);
  }
  while (g < ntiles) {
    const int gn = g + wstride;              // issue next tile's loads NOW
    if (gn < ntiles) {
      const float* p = x + ((size_t)gn * WROWS + lane) * C;
      n0 = *(const f4*)(p);       n1 = *(const f4*)(p + 4);   n2 = *(const f2*)(p + 8);
      m0 = *(const f4*)(p + 640); m1 = *(const f4*)(p + 644); m2 = *(const f2*)(p + 648);
    }
    accum10(a0, a1, a2, s1, s2, sl);         // compute on current regs (no dep on loads)
    accum10(b0, b1, b2, s1, s2, sl);
    a0 = n0; a1 = n1; a2 = n2;               // vmcnt wait lands here, after compute
    b0 = m0; b1 = m1; b2 = m2;
    g = gn;
  }

  if (gwave == wstride - 1) {                // tail rows (none when nrows%128==0)
    for (int rr = tailStart + lane; rr < nrows; rr += 64) {
      const float* r = x + (size_t)rr * C;
      f4 t0 = *(const f4*)(r);
      f4 t1 = *(const f4*)(r + 4);
      f2 t2 = *(const f2*)(r + 8);
      accum10(t0, t1, t2, s1, s2, sl);
    }
  }

  // block reduction: wave shuffle, then cross-wave via LDS (single barrier)
#pragma unroll
  for (int c = 0; c < C; c++) {
    float v1 = s1[c], v2 = s2[c], v3 = sl[c];
#pragma unroll
    for (int off = 32; off >= 1; off >>= 1) {
      v1 += __shfl_down(v1, off);
      v2 += __shfl_down(v2, off);
      v3 += __shfl_down(v3, off);
    }
    if (lane == 0) {
      red[wave][c] = v1;
      red[wave][C + c] = v2;
      red[wave][2 * C + c] = v3;
    }
  }
  __syncthreads();
  if (tid < NSTATS) {
    float tot = red[0][tid] + red[1][tid] + red[2][tid] + red[3][tid];
    partials[(size_t)tid * nblocks + blockIdx.x] = tot;   // SoA over blocks
  }
}

// ---------------- fast fp64 reciprocal: v_rcp_f64 + 2 NR steps (<=1 ulp) --------
// IEEE fp64 divide lowers to ~12 instr (div_scale/rcp/3xNR/div_fmas/div_fixup)
// with a long serial fixup chain. rcp_f64 (~2^-27) + 2 Newton steps reaches
// machine precision in 5 instr with a short chain. All divisors here are
// strictly positive and well-scaled (a>0, y>=8, trigamma>0).

__device__ __forceinline__ double frcp(double x) {
  double r;
  asm("v_rcp_f64 %0, %1" : "=v"(r) : "v"(x));
  double e = fma(-x, r, 1.0);
  r = fma(r, e, r);
  e = fma(-x, r, 1.0);
  r = fma(r, e, r);
  return r;
}

// ---------------- fp64 digamma/trigamma via shift-8 + asymptotic ----------------

__device__ __forceinline__ void digtri8(double x, double& dg, double& tg) {
  double i0 = frcp(x),       i1 = frcp(x + 1.0);
  double i2 = frcp(x + 2.0), i3 = frcp(x + 3.0);
  double i4 = frcp(x + 4.0), i5 = frcp(x + 5.0);
  double i6 = frcp(x + 6.0), i7 = frcp(x + 7.0);
  double rd = (i0 + i1) + (i2 + i3) + ((i4 + i5) + (i6 + i7));
  double rt = (i0 * i0 + i1 * i1) + (i2 * i2 + i3 * i3) +
              ((i4 * i4 + i5 * i5) + (i6 * i6 + i7 * i7));
  double y = x + 8.0;
  double yi = frcp(y), f = yi * yi;
  dg = log(y) - 0.5 * yi
     - f * (1.0 / 12 - f * (1.0 / 120 - f * (1.0 / 252 - f * (1.0 / 240 - f * (1.0 / 132)))))
     - rd;
  tg = rt + yi + 0.5 * f
     + f * yi * (1.0 / 6 - f * (1.0 / 30 - f * (1.0 / 42 - f * (1.0 / 30))));
}

__device__ __forceinline__ double wsum16(double v) {
#pragma unroll
  for (int off = 1; off < 16; off <<= 1) v += __shfl_xor(v, off);
  return v;
}

// ---------------- Kernel 2: coalesced reduce + fast-rcp Newton (fp64) -----------

__global__ __launch_bounds__(1024) void dir_newton_kernel(
    const float* __restrict__ partials, float* __restrict__ out,
    int nparts, double nrows) {
  __shared__ double tot[NSTATS];
  const int tid = threadIdx.x;

  {
    const int j = tid >> 5;        // series (30 active of 32)
    const int k = tid & 31;
    double s = 0.0;
    if (j < NSTATS) {
      const float* __restrict__ base = partials + (size_t)j * nparts;
      const int nv4 = nparts >> 2;
      const f4* __restrict__ b4 = (const f4*)base;
      // coalesced: 32 lanes x 16B = 512B contiguous per instruction
      for (int b = k; b < nv4; b += 32) {
        f4 v = b4[b];
        s += ((double)v.x + (double)v.y) + ((double)v.z + (double)v.w);
      }
      for (int b = (nv4 << 2) + k; b < nparts; b += 32)  // tail (nparts%4!=0 only)
        s += (double)base[b];
    }
#pragma unroll
    for (int off = 16; off >= 1; off >>= 1) s += __shfl_xor(s, off);
    if (j < NSTATS && k == 0) tot[j] = s;
  }
  __syncthreads();

  if (tid < 16) {
    const int c = tid;
    const bool act = (c < C);
    const double n = nrows;
    const double ninv = frcp(n);
    double m1 = 0.0, m2 = 0.0, lpa = 0.0;
    if (act) {
      m1 = tot[c] * ninv;
      m2 = tot[C + c] * ninv;
      lpa = tot[2 * C + c] * ninv;
    }
    double ratio = act ? (m1 - m2) * frcp(m2 - m1 * m1) : 0.0;
    double rmean = wsum16(ratio) * (1.0 / (double)C);
    double a = act ? m1 * rmean : 0.0;

    double diff = 1e30;
    for (int k = 0; k < 100 && diff >= 1e-3; k++) {
      double S = wsum16(a);             // lanes 10..15 hold 0
      double dgl, tgl;                  // lanes 0..9: digtri(a); lane 10+: digtri(S)
      digtri8(act ? a : S, dgl, tgl);
      double dgS = __shfl(dgl, 10);
      double tgS = __shfl(tgl, 10);
      double g = act ? (dgS - dgl + lpa) * n : 0.0;
      double qinv = act ? -frcp(n * tgl) : 0.0;
      double z = n * tgS;
      double num = wsum16(g * qinv);
      double sq = wsum16(qinv);
      // b = num / (1/z + sq) = num * z / (1 + z*sq)   (one reciprocal)
      double b = num * z * frcp(fma(z, sq, 1.0));
      double anew = act ? a - (g - b) * qinv : 0.0;
      diff = wsum16(fabs(anew - a));
      a = anew;
    }
    if (act) out[c] = (float)a;
  }
}

// ---------------- launch ----------------

extern "C" void kernel_launch(void* const* d_in, const int* in_sizes, int n_in,
                              void* d_out, int out_size, void* d_ws, size_t ws_size,
                              hipStream_t stream) {
  const float* x = (const float*)d_in[0];
  const int total = in_sizes[0];
  const int nrows = total / C;

  int grid = NBLOCKS;
  size_t need = (size_t)NSTATS * grid * sizeof(float);
  if (need > ws_size) {
    grid = (int)(ws_size / (NSTATS * sizeof(float)));
    if (grid < 1) grid = 1;
  }

  float* partials = (float*)d_ws;
  dir_stats_kernel<<<grid, BLOCK, 0, stream>>>(x, partials, nrows, grid);
  dir_newton_kernel<<<1, 1024, 0, stream>>>(partials, (float*)d_out, grid, (double)nrows);
}